// Round 7
// baseline (36.497 us; speedup 1.0000x reference)
//
#include <hip/hip_runtime.h>

#define TLEN 4096
#define NT 256              // 4 waves per block
#define SEG 1024            // elements per wave-segment
#define OFF 24              // left-halo capacity (need 21)
#define RHW 32              // right-halo staged (need 28)
#define BUFW 1088           // per-buffer width in floats (>= OFF+SEG+RHW)

typedef float f32x4 __attribute__((ext_vector_type(4)));
typedef float f32x2 __attribute__((ext_vector_type(2)));

__device__ __forceinline__ f32x4 ldv4(const float* p) {
    return *reinterpret_cast<const f32x4*>(p);
}

__global__ __launch_bounds__(NT, 4) void swt_db4_l3_kernel(
    const float* __restrict__ x,
    const float* __restrict__ lo_g,
    const float* __restrict__ hi_g,
    float* __restrict__ out)
{
    __shared__ float lds[4 * 2 * BUFW];

    const int wave = threadIdx.x >> 6;
    const int lane = threadIdx.x & 63;
    const int row  = blockIdx.x;
    const int seg  = wave * SEG;          // segment start within row

    float* bufX = &lds[wave * 2 * BUFW];  // x, later A2 (private to this wave)
    float* bufY = bufX + BUFW;            // A1

    // packed (lo, hi) filter pairs; uniform addresses -> scalar loads
    f32x2 c[8];
#pragma unroll
    for (int j = 0; j < 8; ++j) { c[j].x = lo_g[j]; c[j].y = hi_g[j]; }

    const float* xr = x + (size_t)row * TLEN;

    // ---- Stage segment + wrap halos into bufX (no barrier needed: wave-private) ----
#pragma unroll
    for (int k = 0; k < 4; ++k) {
        int q = lane + k * 64;                       // quad index 0..255
        *reinterpret_cast<f32x4*>(&bufX[OFF + 4 * q]) = ldv4(xr + seg + 4 * q);
    }
    if (lane < OFF)   // left halo: u in [-24, 0)
        bufX[lane] = xr[(seg - OFF + lane) & (TLEN - 1)];
    if (lane < RHW)   // right halo: u in [1024, 1056)
        bufX[OFF + SEG + lane] = xr[(seg + SEG + lane) & (TLEN - 1)];

    float D1e[18], D2e[18];

    // ---- Level 1 (dil=1): A1[u] -> bufY, D1 -> regs, u in [-18, 1048) ----
    // iterate u = -64 + lane + 64k, k = 0..17 (shift of exactly one lane-stride
    // so owned t = lane + 64k' maps to extended iter k = k'+1 in the SAME lane)
#pragma unroll
    for (int k = 0; k < 18; ++k) {
        int u = -64 + lane + 64 * k;
        f32x2 acc; acc.x = 0.f; acc.y = 0.f;
        bool act = (k > 0 && k < 17) || (u >= -18 && u < 1048);
        if (act) {
            const float* s = &bufX[OFF + u];
#pragma unroll
            for (int j = 0; j < 8; ++j) {
                float v = s[4 - j];
                f32x2 vv; vv.x = v; vv.y = v;
                acc = __builtin_elementwise_fma(c[j], vv, acc);
            }
            bufY[OFF + u] = acc.x;
        }
        D1e[k] = acc.y;
    }

    // ---- Level 2 (dil=2): A2[u] -> bufX (x is dead), D2 -> regs, u in [-12, 1040) ----
#pragma unroll
    for (int k = 0; k < 18; ++k) {
        int u = -64 + lane + 64 * k;
        f32x2 acc; acc.x = 0.f; acc.y = 0.f;
        bool act = (k > 0 && k < 17) || (u >= -12 && u < 1040);
        if (act) {
            const float* s = &bufY[OFF + u];
#pragma unroll
            for (int j = 0; j < 8; ++j) {
                float v = s[(4 - j) * 2];
                f32x2 vv; vv.x = v; vv.y = v;
                acc = __builtin_elementwise_fma(c[j], vv, acc);
            }
            bufX[OFF + u] = acc.x;
        }
        D2e[k] = acc.y;
    }

    // ---- Level 3 (dil=4): owned range only, t = lane + 64k, k = 0..15; fused store ----
    f32x4* outr = reinterpret_cast<f32x4*>(out + (size_t)row * TLEN * 4) + seg;
#pragma unroll
    for (int k = 0; k < 16; ++k) {
        int t = lane + 64 * k;
        const float* s = &bufX[OFF + t];
        f32x2 acc; acc.x = 0.f; acc.y = 0.f;
#pragma unroll
        for (int j = 0; j < 8; ++j) {
            float v = s[(4 - j) * 4];
            f32x2 vv; vv.x = v; vv.y = v;
            acc = __builtin_elementwise_fma(c[j], vv, acc);
        }
        f32x4 o;
        o.x = acc.x;        // A3
        o.y = acc.y;        // D3
        o.z = D2e[k + 1];   // D2 (same lane, extended iter k+1)
        o.w = D1e[k + 1];   // D1
        outr[t] = o;
    }
}

extern "C" void kernel_launch(void* const* d_in, const int* in_sizes, int n_in,
                              void* d_out, int out_size, void* d_ws, size_t ws_size,
                              hipStream_t stream) {
    const float* x  = (const float*)d_in[0];
    const float* lo = (const float*)d_in[1];
    const float* hi = (const float*)d_in[2];
    float* out = (float*)d_out;

    const int rows = 64 * 32;   // B * N
    swt_db4_l3_kernel<<<dim3(rows), dim3(NT), 0, stream>>>(x, lo, hi, out);
}

// Round 8
// 32.426 us; speedup vs baseline: 1.1256x; 1.1256x over previous
//
#include <hip/hip_runtime.h>

#define TLEN 4096
#define NT 256
#define SEG 2048
#define PER 8              // owned elements per thread
#define OFF 24             // left halo capacity (x needs 21, A1 18, A2 12)
#define BUFW 2112          // 24 + 2048 + 28 = 2100, padded

typedef float f32x4 __attribute__((ext_vector_type(4)));
typedef float f32x2 __attribute__((ext_vector_type(2)));

__device__ __forceinline__ f32x4 ldv4(const float* p) {
    return *reinterpret_cast<const f32x4*>(p);
}

__global__ __launch_bounds__(NT, 8) void swt_db4_l3_kernel(
    const float* __restrict__ x,
    const float* __restrict__ lo_g,
    const float* __restrict__ hi_g,
    float* __restrict__ out)
{
    __shared__ float bufX[BUFW];   // x, later A2
    __shared__ float bufY[BUFW];   // A1

    const int bid = blockIdx.x;
    const int row = bid >> 1;
    const int seg = (bid & 1) << 11;     // 0 or 2048
    const int tid = threadIdx.x;

    // packed (lo, hi) filter pairs; uniform addresses -> scalar regs
    f32x2 c[8];
#pragma unroll
    for (int j = 0; j < 8; ++j) { c[j].x = lo_g[j]; c[j].y = hi_g[j]; }

    const float* xr = x + (size_t)row * TLEN;

    // ---- Stage owned x (coalesced float4) + wrap halo (wave 0 only) ----
#pragma unroll
    for (int k = 0; k < 2; ++k) {
        int idx = (tid + k * NT) * 4;
        *reinterpret_cast<f32x4*>(&bufX[OFF + idx]) = ldv4(xr + seg + idx);
    }
    if (tid < 49) {   // x halo: u in [-21,-1] and [2048,2076)
        int u = (tid < 21) ? (tid - 21) : (SEG + tid - 21);
        bufX[OFF + u] = xr[(seg + u) & (TLEN - 1)];
    }
    __syncthreads();

    float D1[PER], D2[PER];

    // ---- Level 1 (dil=1): bufX -> bufY, D1 regs ----
#pragma unroll
    for (int k = 0; k < PER; ++k) {
        int t = tid + k * NT;
        const float* s = &bufX[OFF + t];
        f32x2 acc; acc.x = 0.f; acc.y = 0.f;
#pragma unroll
        for (int j = 0; j < 8; ++j) {
            float v = s[4 - j];
            f32x2 vv; vv.x = v; vv.y = v;
            acc = __builtin_elementwise_fma(c[j], vv, acc);
        }
        bufY[OFF + t] = acc.x;
        D1[k] = acc.y;
    }
    if (tid < 42) {   // edge A1 (A only): u in [-18,-1] and [2048,2072)
        int u = (tid < 18) ? (tid - 18) : (SEG + tid - 18);
        const float* s = &bufX[OFF + u];
        float a = 0.f;
#pragma unroll
        for (int j = 0; j < 8; ++j) a = fmaf(c[j].x, s[4 - j], a);
        bufY[OFF + u] = a;
    }
    __syncthreads();

    // ---- Level 2 (dil=2): bufY -> bufX (x dead), D2 regs ----
#pragma unroll
    for (int k = 0; k < PER; ++k) {
        int t = tid + k * NT;
        const float* s = &bufY[OFF + t];
        f32x2 acc; acc.x = 0.f; acc.y = 0.f;
#pragma unroll
        for (int j = 0; j < 8; ++j) {
            float v = s[(4 - j) * 2];
            f32x2 vv; vv.x = v; vv.y = v;
            acc = __builtin_elementwise_fma(c[j], vv, acc);
        }
        bufX[OFF + t] = acc.x;
        D2[k] = acc.y;
    }
    if (tid < 28) {   // edge A2 (A only): u in [-12,-1] and [2048,2064)
        int u = (tid < 12) ? (tid - 12) : (SEG + tid - 12);
        const float* s = &bufY[OFF + u];
        float a = 0.f;
#pragma unroll
        for (int j = 0; j < 8; ++j) a = fmaf(c[j].x, s[(4 - j) * 2], a);
        bufX[OFF + u] = a;
    }
    __syncthreads();

    // ---- Level 3 (dil=4): owned only; fused float4 store ----
    f32x4* outr = reinterpret_cast<f32x4*>(out + (size_t)row * TLEN * 4) + seg;
#pragma unroll
    for (int k = 0; k < PER; ++k) {
        int t = tid + k * NT;
        const float* s = &bufX[OFF + t];
        f32x2 acc; acc.x = 0.f; acc.y = 0.f;
#pragma unroll
        for (int j = 0; j < 8; ++j) {
            float v = s[(4 - j) * 4];
            f32x2 vv; vv.x = v; vv.y = v;
            acc = __builtin_elementwise_fma(c[j], vv, acc);
        }
        f32x4 o;
        o.x = acc.x;    // A3
        o.y = acc.y;    // D3
        o.z = D2[k];
        o.w = D1[k];
        outr[t] = o;
    }
}

extern "C" void kernel_launch(void* const* d_in, const int* in_sizes, int n_in,
                              void* d_out, int out_size, void* d_ws, size_t ws_size,
                              hipStream_t stream) {
    const float* x  = (const float*)d_in[0];
    const float* lo = (const float*)d_in[1];
    const float* hi = (const float*)d_in[2];
    float* out = (float*)d_out;

    const int nblocks = 64 * 32 * 2;   // 2 blocks per row
    swt_db4_l3_kernel<<<dim3(nblocks), dim3(NT), 0, stream>>>(x, lo, hi, out);
}